// Round 5
// baseline (191.451 us; speedup 1.0000x reference)
//
#include <hip/hip_runtime.h>
#include <hip/hip_bf16.h>

typedef unsigned int uint32;
typedef unsigned short ushort;
typedef __attribute__((ext_vector_type(4))) float floatx4;
typedef __attribute__((ext_vector_type(8))) __bf16 bf16x8;

#define NPTS 8192
#define HSZ 524288   // 16384*32 elements per head slice (q, bias)
#define HSZ2 1048576 // 16384*64 elements per head slice (interleaved K|V)

// ---------------- bf16 helpers (RNE) ----------------
__device__ __forceinline__ ushort f2bf(float f) {
    uint32 u = __float_as_uint(f);
    uint32 r = (u + 0x7fffu + ((u >> 16) & 1u)) >> 16;
    return (ushort)r;
}
__device__ __forceinline__ float bf1(ushort u) { return __uint_as_float((uint32)u << 16); }
__device__ __forceinline__ float bflo(uint32 u) { return __uint_as_float(u << 16); }
__device__ __forceinline__ float bfhi(uint32 u) { return __uint_as_float(u & 0xffff0000u); }

// ---------------- prep: cast x -> bf16 | pack weights (MLP moved into gemm launch) ----------------
__global__ __launch_bounds__(256) void prep_kernel(
    const float* __restrict__ x,
    const float* __restrict__ Wq, const float* __restrict__ Wk,
    const float* __restrict__ Wv, const float* __restrict__ Wo,
    const float* __restrict__ bq, const float* __restrict__ bk, const float* __restrict__ bv,
    ushort* __restrict__ xb, ushort* __restrict__ Wqkvt, ushort* __restrict__ Wot,
    float* __restrict__ biasqkv) {
    const int bi = blockIdx.x;
    const int tid = threadIdx.x;
    if (bi < 4096) {
        int i = (bi * 256 + tid) * 4;
        float4 v = *(const float4*)(x + i);
        ushort4 o;
        o.x = f2bf(v.x); o.y = f2bf(v.y); o.z = f2bf(v.z); o.w = f2bf(v.w);
        *(ushort4*)(xb + i) = o;
    } else {
        int f = (bi - 4096) * 256 + tid;  // 0 .. 262143
        if (f < 768 * 256) {
            int n = f >> 8, k = f & 255;
            int seg = n >> 8, nc = n & 255;
            const float* W = (seg == 0) ? Wq : (seg == 1) ? Wk : Wv;
            Wqkvt[f] = f2bf(W[k * 256 + nc]);
        } else {
            int g = f - 768 * 256;
            int n = g >> 8, k = g & 255;
            Wot[g] = f2bf(Wo[k * 256 + n]);
        }
        if (f < 768) biasqkv[f] = (f < 256) ? bq[f] : (f < 512) ? bk[f - 256] : bv[f - 512];
    }
}

// ---------------- fused QKV GEMM + bias-MLP (concurrent block families) ----------------
// blocks 0..767   : 128x128-tile GEMM, BK=64, XOR-swizzled LDS; scatter head-major
//                   qh[h][p][32], kvh[h][p][64] (K dims 0-31, V dims 32-63, one line)
// blocks 768..2815: bias MLP, 8 points/block, head-major bias_hg[h][p][32].
// The two families have disjoint outputs and no inter-block dependency: the MLP
// rides in the GEMM's occupancy shadow instead of a serialized prep phase.
__global__ __launch_bounds__(256) void gemm_qkv_mlp(
    const ushort* __restrict__ A, const ushort* __restrict__ Wt,
    const float* __restrict__ bias,
    ushort* __restrict__ qh, ushort* __restrict__ kvh,
    const float* __restrict__ xyz, const int* __restrict__ idx,
    const float* __restrict__ W1, const float* __restrict__ b1,
    const float* __restrict__ W2, const float* __restrict__ b2,
    ushort* __restrict__ bias_hg) {
    __shared__ __align__(16) ushort As[128 * 64];
    __shared__ __align__(16) ushort Bs[128 * 64];
    const int bi = blockIdx.x;
    const int tid = threadIdx.x;

    if (bi >= 768) {
        // ---- bias MLP branch (LDS overlaid on As) ----
        float* W1s = (float*)As;        // 96
        float* b1s = W1s + 96;          // 32
        float* W2s = b1s + 32;          // 256
        float* b2s = W2s + 256;         // 8
        if (tid < 96) W1s[tid] = W1[tid];
        if (tid < 32) b1s[tid] = b1[tid];
        W2s[tid] = W2[tid];
        if (tid < 8) b2s[tid] = b2[tid];
        __syncthreads();
        const int wid = tid >> 6, lane = tid & 63;
        const int s = lane >> 5, j = lane & 31;
        const int p = (bi - 768) * 8 + wid * 2 + s;
        const int b = p >> 13, n = p & 8191;
        const int nj = idx[(size_t)p * 32 + j];
        const size_t pb = ((size_t)b * NPTS + n) * 3;
        const size_t nb = ((size_t)b * NPTS + nj) * 3;
        const float rx = xyz[pb + 0] - xyz[nb + 0];
        const float ry = xyz[pb + 1] - xyz[nb + 1];
        const float rz = xyz[pb + 2] - xyz[nb + 2];
        float acc[8];
#pragma unroll
        for (int h = 0; h < 8; ++h) acc[h] = b2s[h];
#pragma unroll
        for (int u = 0; u < 32; ++u) {
            float hv = rx * W1s[u] + ry * W1s[32 + u] + rz * W1s[64 + u] + b1s[u];
            hv = fmaxf(hv, 0.f);
#pragma unroll
            for (int h = 0; h < 8; ++h) acc[h] += hv * W2s[u * 8 + h];
        }
#pragma unroll
        for (int h = 0; h < 8; ++h) bias_hg[(size_t)h * HSZ + p * 32 + j] = f2bf(acc[h]);
        return;
    }

    // ---- GEMM branch ----
    const int w = tid >> 6, lane = tid & 63;
    const int m0 = (bi / 6) * 128, n0 = (bi % 6) * 128;
    const int wm = (w & 1) * 64, wn = (w >> 1) * 64;

    floatx4 acc[4][4] = {};

    for (int kt = 0; kt < 256; kt += 64) {
        __syncthreads();
#pragma unroll
        for (int c4 = 0; c4 < 4; ++c4) {
            const int c = w * 4 + c4;
            const int r = c * 8 + (lane >> 3);
            const int gseg = (lane & 7) ^ (r & 7);
            const char* ga = (const char*)(A + (size_t)(m0 + r) * 256 + kt) + gseg * 16;
            const char* gb = (const char*)(Wt + (size_t)(n0 + r) * 256 + kt) + gseg * 16;
            __builtin_amdgcn_global_load_lds((const __attribute__((address_space(1))) void*)ga,
                                             (__attribute__((address_space(3))) void*)((char*)As + c * 1024),
                                             16, 0, 0);
            __builtin_amdgcn_global_load_lds((const __attribute__((address_space(1))) void*)gb,
                                             (__attribute__((address_space(3))) void*)((char*)Bs + c * 1024),
                                             16, 0, 0);
        }
        __syncthreads();

        bf16x8 af[2][4], bg[2][4];
#pragma unroll
        for (int kk = 0; kk < 2; ++kk) {
            const int s = kk * 4 + (lane >> 4);
            const int phys = s ^ (lane & 7);
#pragma unroll
            for (int i = 0; i < 4; ++i) {
                af[kk][i] = *(const bf16x8*)((const char*)As + (wm + i * 16 + (lane & 15)) * 128 + phys * 16);
                bg[kk][i] = *(const bf16x8*)((const char*)Bs + (wn + i * 16 + (lane & 15)) * 128 + phys * 16);
            }
        }
#pragma unroll
        for (int kk = 0; kk < 2; ++kk)
#pragma unroll
            for (int mi = 0; mi < 4; ++mi)
#pragma unroll
                for (int ni = 0; ni < 4; ++ni)
                    acc[mi][ni] = __builtin_amdgcn_mfma_f32_16x16x32_bf16(af[kk][mi], bg[kk][ni], acc[mi][ni], 0, 0, 0);
    }

#pragma unroll
    for (int ni = 0; ni < 4; ++ni) {
        const int col = n0 + wn + ni * 16 + (lane & 15);  // 0..767
        const int seg = col >> 8;
        const int head = (col >> 5) & 7;
        const int dim = (col & 31) + ((seg == 2) ? 32 : 0);
        const float bv = bias[col];
#pragma unroll
        for (int mi = 0; mi < 4; ++mi) {
            const int row0 = m0 + wm + mi * 16 + (lane >> 4) * 4;
#pragma unroll
            for (int r = 0; r < 4; ++r) {
                const int row = row0 + r;
                const ushort val = f2bf(acc[mi][ni][r] + bv);
                if (seg == 0)
                    qh[(size_t)head * HSZ + (size_t)row * 32 + dim] = val;
                else
                    kvh[(size_t)head * HSZ2 + (size_t)row * 64 + dim] = val;
            }
        }
    }
}

// ---------------- O-proj GEMM, 64x64 tile ----------------
__global__ __launch_bounds__(256) void gemm_mfma64(const ushort* __restrict__ A,
                                                   const ushort* __restrict__ Wt,
                                                   const float* __restrict__ bias,
                                                   float* __restrict__ outv, int N) {
    __shared__ __align__(16) ushort As[64 * 32];
    __shared__ __align__(16) ushort Bs[64 * 32];
    const int tid = threadIdx.x;
    const int w = tid >> 6, lane = tid & 63;
    const int m0 = blockIdx.y * 64, n0 = blockIdx.x * 64;
    const int row = tid >> 2;
    const int col16 = (tid & 3) * 16;

    floatx4 acc[4] = {};

    for (int kt = 0; kt < 256; kt += 32) {
        __syncthreads();
        {
            const char* ga = (const char*)(A + (size_t)(m0 + row) * 256 + kt) + col16;
            const char* gb = (const char*)(Wt + (size_t)(n0 + row) * 256 + kt) + col16;
            __builtin_amdgcn_global_load_lds((const __attribute__((address_space(1))) void*)ga,
                                             (__attribute__((address_space(3))) void*)((char*)As + w * 1024),
                                             16, 0, 0);
            __builtin_amdgcn_global_load_lds((const __attribute__((address_space(1))) void*)gb,
                                             (__attribute__((address_space(3))) void*)((char*)Bs + w * 1024),
                                             16, 0, 0);
        }
        __syncthreads();

        bf16x8 af = *(const bf16x8*)&As[(w * 16 + (lane & 15)) * 32 + (lane >> 4) * 8];
        bf16x8 bg[4];
#pragma unroll
        for (int ni = 0; ni < 4; ++ni)
            bg[ni] = *(const bf16x8*)&Bs[(ni * 16 + (lane & 15)) * 32 + (lane >> 4) * 8];
#pragma unroll
        for (int ni = 0; ni < 4; ++ni)
            acc[ni] = __builtin_amdgcn_mfma_f32_16x16x32_bf16(af, bg[ni], acc[ni], 0, 0, 0);
    }

#pragma unroll
    for (int ni = 0; ni < 4; ++ni) {
        const int col = n0 + ni * 16 + (lane & 15);
        const float bv = bias[col];
        const int row0 = m0 + w * 16 + (lane >> 4) * 4;
#pragma unroll
        for (int r = 0; r < 4; ++r)
            outv[(size_t)(row0 + r) * N + col] = acc[ni][r] + bv;
    }
}

// ---------------- attention: time-phased heads, interleaved K|V rows ----------------
// blockIdx = head*1024 + pg: resident blocks cluster on 1-2 heads so each XCD's
// L2 holds the current head's K|V slice (2 MB).
//
// LDS-free. Lane mapping: s = point (lane>>4), g = neighbor group (lane>>2 & 3),
// q4 = row quarter (lane&3). 4 points/wave, 8 neighbors/lane. Each neighbor's
// K and V live in ONE 128-B line (kvh row): the V load L1-hits the K load's line.
// All 16 scattered loads are issued before any compute — one latency exposure.
__global__ __launch_bounds__(256) void attn_kernel(
    const ushort* __restrict__ qh, const ushort* __restrict__ kvh,
    const int* __restrict__ idx, const ushort* __restrict__ bias_hg, ushort* __restrict__ out) {
    const int tid = threadIdx.x, wid = tid >> 6, lane = tid & 63;
    const int h = blockIdx.x >> 10;       // head phase (slow-varying)
    const int pg = blockIdx.x & 1023;
    const int pbase = pg * 16 + wid * 4;

    const char* kv_h = (const char*)(kvh + (size_t)h * HSZ2);

    const int s = lane >> 4;
    const int g = (lane >> 2) & 3, q4 = lane & 3;
    const int p = pbase + s;
    const int b = p >> 13;

    // ---- load phase: everything this lane needs, issued up front ----
    const int4 n0 = *(const int4*)(idx + (size_t)p * 32 + g * 8);
    const int4 n1 = *(const int4*)(idx + (size_t)p * 32 + g * 8 + 4);
    const uint4 qp = *(const uint4*)(qh + (size_t)h * HSZ + p * 32 + q4 * 8);
    const uint4 bs = *(const uint4*)(bias_hg + (size_t)h * HSZ + p * 32 + g * 8);

    const uint32 roff = (uint32)(b * NPTS);
    uint32 addr[8];
    addr[0] = ((uint32)n0.x + roff) * 128u + q4 * 16;
    addr[1] = ((uint32)n0.y + roff) * 128u + q4 * 16;
    addr[2] = ((uint32)n0.z + roff) * 128u + q4 * 16;
    addr[3] = ((uint32)n0.w + roff) * 128u + q4 * 16;
    addr[4] = ((uint32)n1.x + roff) * 128u + q4 * 16;
    addr[5] = ((uint32)n1.y + roff) * 128u + q4 * 16;
    addr[6] = ((uint32)n1.z + roff) * 128u + q4 * 16;
    addr[7] = ((uint32)n1.w + roff) * 128u + q4 * 16;

    uint4 kreg[8], vreg[8];
#pragma unroll
    for (int i = 0; i < 8; ++i) kreg[i] = *(const uint4*)(kv_h + addr[i]);
#pragma unroll
    for (int i = 0; i < 8; ++i) vreg[i] = *(const uint4*)(kv_h + addr[i] + 64);

    // unpack q (this lane's 8 dims of the 32-dim row)
    const float4 qa = {bflo(qp.x), bfhi(qp.x), bflo(qp.y), bfhi(qp.y)};
    const float4 qb = {bflo(qp.z), bfhi(qp.z), bflo(qp.w), bfhi(qp.w)};

    // ---- score phase: 4 q4-lanes cooperate on each K row ----
    float e_r[8];
    float esum = 0.f;
#pragma unroll
    for (int i = 0; i < 8; ++i) {
        const uint4 kv = kreg[i];
        float d = bflo(kv.x) * qa.x + bfhi(kv.x) * qa.y
                + bflo(kv.y) * qa.z + bfhi(kv.y) * qa.w
                + bflo(kv.z) * qb.x + bfhi(kv.z) * qb.y
                + bflo(kv.w) * qb.z + bfhi(kv.w) * qb.w;
        // complete the 32-dim dot across the 4 q4 lanes
        d += __shfl_xor(d, 1, 64);
        d += __shfl_xor(d, 2, 64);
        const uint32 bw = (i < 2) ? bs.x : (i < 4) ? bs.y : (i < 6) ? bs.z : bs.w;
        const float bb = (i & 1) ? bfhi(bw) : bflo(bw);
        const float e = __expf(d * 0.17677669529663687f + bb);
        e_r[i] = e;
        esum += e;
    }
    // per-point softmax denominator: reduce over g (bits 2..3); q4 copies identical
    float ssum = esum;
    ssum += __shfl_xor(ssum, 4, 64);
    ssum += __shfl_xor(ssum, 8, 64);
    const float rinv = __builtin_amdgcn_rcpf(ssum);

    // ---- PV phase: same lane mapping; V already in registers ----
    float a0 = 0.f, a1 = 0.f, a2 = 0.f, a3 = 0.f, a4 = 0.f, a5 = 0.f, a6 = 0.f, a7 = 0.f;
#pragma unroll
    for (int i = 0; i < 8; ++i) {
        const float wgt = e_r[i];
        const uint4 v = vreg[i];
        a0 += wgt * bflo(v.x); a1 += wgt * bfhi(v.x);
        a2 += wgt * bflo(v.y); a3 += wgt * bfhi(v.y);
        a4 += wgt * bflo(v.z); a5 += wgt * bfhi(v.z);
        a6 += wgt * bflo(v.w); a7 += wgt * bfhi(v.w);
    }
    // dim-splitting butterfly over g bits (4, 8): 8 dims -> 2 dims/lane
    const bool hi4 = (lane & 4) != 0;
    {
        float t0 = hi4 ? a0 : a4, t1 = hi4 ? a1 : a5, t2 = hi4 ? a2 : a6, t3 = hi4 ? a3 : a7;
        float k0 = hi4 ? a4 : a0, k1 = hi4 ? a5 : a1, k2 = hi4 ? a6 : a2, k3 = hi4 ? a7 : a3;
        a0 = k0 + __shfl_xor(t0, 4, 64);
        a1 = k1 + __shfl_xor(t1, 4, 64);
        a2 = k2 + __shfl_xor(t2, 4, 64);
        a3 = k3 + __shfl_xor(t3, 4, 64);
    }
    const bool hi8 = (lane & 8) != 0;
    {
        float t0 = hi8 ? a0 : a2, t1 = hi8 ? a1 : a3;
        float k0 = hi8 ? a2 : a0, k1 = hi8 ? a3 : a1;
        a0 = k0 + __shfl_xor(t0, 8, 64);
        a1 = k1 + __shfl_xor(t1, 8, 64);
    }
    // lane holds dims D, D+1 with D = q4*8 + (hi4?4:0) + (hi8?2:0); packed store,
    // all 64 lanes active: 16 lanes x 4 B = 64 B contiguous per point.
    const int D = q4 * 8 + (hi4 ? 4 : 0) + (hi8 ? 2 : 0);
    const uint32 u = (uint32)f2bf(a0 * rinv) | ((uint32)f2bf(a1 * rinv) << 16);
    *(uint32*)(out + (size_t)p * 256 + h * 32 + D) = u;
}

// ---------------- launch ----------------
extern "C" void kernel_launch(void* const* d_in, const int* in_sizes, int n_in,
                              void* d_out, int out_size, void* d_ws, size_t ws_size,
                              hipStream_t stream) {
    const float* x   = (const float*)d_in[0];
    const float* xyz = (const float*)d_in[1];
    const int*   idx = (const int*)d_in[2];
    const float* Wq = (const float*)d_in[3];
    const float* bq = (const float*)d_in[4];
    const float* Wk = (const float*)d_in[5];
    const float* bk = (const float*)d_in[6];
    const float* Wv = (const float*)d_in[7];
    const float* bv = (const float*)d_in[8];
    const float* Wo = (const float*)d_in[9];
    const float* bo = (const float*)d_in[10];
    const float* W1 = (const float*)d_in[11];
    const float* b1 = (const float*)d_in[12];
    const float* W2 = (const float*)d_in[13];
    const float* b2 = (const float*)d_in[14];

    char* wsb = (char*)d_ws;
    ushort* x_bf    = (ushort*)wsb;                   // 8 MB (aliased by aout_bf)
    ushort* aout_bf = x_bf;                           // x consumed by gemm before attn writes
    ushort* qh      = (ushort*)(wsb + 8388608);       // 8 MB [8][16384][32]
    ushort* kvh     = (ushort*)(wsb + 16777216);      // 16 MB [8][16384][64] (K|V interleaved)
    ushort* bias_hg = (ushort*)(wsb + 33554432);      // 8 MB [8][16384][32]
    ushort* Wqkvt   = (ushort*)(wsb + 41943040);      // 384 KB
    ushort* Wot     = (ushort*)(wsb + 42336256);      // 128 KB
    float*  biasqkv = (float*)(wsb + 42467328);       // 3 KB

    prep_kernel<<<5120, 256, 0, stream>>>(x, Wq, Wk, Wv, Wo, bq, bk, bv,
                                          x_bf, Wqkvt, Wot, biasqkv);

    gemm_qkv_mlp<<<2816, 256, 0, stream>>>(x_bf, Wqkvt, biasqkv, qh, kvh,
                                           xyz, idx, W1, b1, W2, b2, bias_hg);

    attn_kernel<<<8192, 256, 0, stream>>>(qh, kvh, idx, bias_hg, aout_bf);

    gemm_mfma64<<<dim3(4, 256), 256, 0, stream>>>(aout_bf, Wot, bo, (float*)d_out, 256);
}

// Round 6
// 184.257 us; speedup vs baseline: 1.0390x; 1.0390x over previous
//
#include <hip/hip_runtime.h>
#include <hip/hip_bf16.h>

typedef unsigned int uint32;
typedef unsigned short ushort;
typedef __attribute__((ext_vector_type(4))) float floatx4;
typedef __attribute__((ext_vector_type(8))) __bf16 bf16x8;

#define NPTS 8192
#define HSZ 524288   // 16384*32 elements per head slice (q, bias)
#define HSZ2 1048576 // 16384*64 elements per head slice (interleaved K|V)

// ---------------- bf16 helpers (RNE) ----------------
__device__ __forceinline__ ushort f2bf(float f) {
    uint32 u = __float_as_uint(f);
    uint32 r = (u + 0x7fffu + ((u >> 16) & 1u)) >> 16;
    return (ushort)r;
}
__device__ __forceinline__ float bf1(ushort u) { return __uint_as_float((uint32)u << 16); }
__device__ __forceinline__ float bflo(uint32 u) { return __uint_as_float(u << 16); }
__device__ __forceinline__ float bfhi(uint32 u) { return __uint_as_float(u & 0xffff0000u); }

// ---------------- prep: cast x -> bf16 | pack weights | bias-MLP (head-major) ----------------
__global__ __launch_bounds__(256) void prep_kernel(
    const float* __restrict__ x, const float* __restrict__ xyz, const int* __restrict__ idx,
    const float* __restrict__ Wq, const float* __restrict__ Wk,
    const float* __restrict__ Wv, const float* __restrict__ Wo,
    const float* __restrict__ bq, const float* __restrict__ bk, const float* __restrict__ bv,
    const float* __restrict__ W1, const float* __restrict__ b1,
    const float* __restrict__ W2, const float* __restrict__ b2,
    ushort* __restrict__ xb, ushort* __restrict__ Wqkvt, ushort* __restrict__ Wot,
    float* __restrict__ biasqkv, ushort* __restrict__ bias_hg) {
    const int bi = blockIdx.x;
    const int tid = threadIdx.x;
    if (bi < 4096) {
        int i = (bi * 256 + tid) * 4;
        float4 v = *(const float4*)(x + i);
        ushort4 o;
        o.x = f2bf(v.x); o.y = f2bf(v.y); o.z = f2bf(v.z); o.w = f2bf(v.w);
        *(ushort4*)(xb + i) = o;
    } else if (bi < 5120) {
        int f = (bi - 4096) * 256 + tid;  // 0 .. 262143
        if (f < 768 * 256) {
            int n = f >> 8, k = f & 255;
            int seg = n >> 8, nc = n & 255;
            const float* W = (seg == 0) ? Wq : (seg == 1) ? Wk : Wv;
            Wqkvt[f] = f2bf(W[k * 256 + nc]);
        } else {
            int g = f - 768 * 256;
            int n = g >> 8, k = g & 255;
            Wot[g] = f2bf(Wo[k * 256 + n]);
        }
        if (f < 768) biasqkv[f] = (f < 256) ? bq[f] : (f < 512) ? bk[f - 256] : bv[f - 512];
    } else {
        // bias MLP: 8 points per block, 2 per wave; head-major output [h][p][j]
        __shared__ float W1s[96], b1s[32], W2s[256], b2s[8];
        if (tid < 96) W1s[tid] = W1[tid];
        if (tid < 32) b1s[tid] = b1[tid];
        W2s[tid] = W2[tid];
        if (tid < 8) b2s[tid] = b2[tid];
        __syncthreads();
        const int wid = tid >> 6, lane = tid & 63;
        const int s = lane >> 5, j = lane & 31;
        const int p = (bi - 5120) * 8 + wid * 2 + s;
        const int b = p >> 13, n = p & 8191;
        const int nj = idx[(size_t)p * 32 + j];
        const size_t pb = ((size_t)b * NPTS + n) * 3;
        const size_t nb = ((size_t)b * NPTS + nj) * 3;
        const float rx = xyz[pb + 0] - xyz[nb + 0];
        const float ry = xyz[pb + 1] - xyz[nb + 1];
        const float rz = xyz[pb + 2] - xyz[nb + 2];
        float acc[8];
#pragma unroll
        for (int h = 0; h < 8; ++h) acc[h] = b2s[h];
#pragma unroll
        for (int u = 0; u < 32; ++u) {
            float hv = rx * W1s[u] + ry * W1s[32 + u] + rz * W1s[64 + u] + b1s[u];
            hv = fmaxf(hv, 0.f);
#pragma unroll
            for (int h = 0; h < 8; ++h) acc[h] += hv * W2s[u * 8 + h];
        }
#pragma unroll
        for (int h = 0; h < 8; ++h) bias_hg[(size_t)h * HSZ + p * 32 + j] = f2bf(acc[h]);
    }
}

// ---------------- QKV GEMM: 128x128 tile, BK=64, XOR-swizzled LDS ----------------
// out scattered head-major: qh[h][p][32]; kvh[h][p][64] with K in dims 0-31, V in 32-63
// (one 128-B cache line holds both K and V rows of a neighbor).
__global__ __launch_bounds__(256) void gemm_qkv(const ushort* __restrict__ A,
                                                const ushort* __restrict__ Wt,
                                                const float* __restrict__ bias,
                                                ushort* __restrict__ qh,
                                                ushort* __restrict__ kvh) {
    __shared__ __align__(16) ushort As[128 * 64];
    __shared__ __align__(16) ushort Bs[128 * 64];
    const int tid = threadIdx.x;
    const int w = tid >> 6, lane = tid & 63;
    const int m0 = blockIdx.y * 128, n0 = blockIdx.x * 128;
    const int wm = (w & 1) * 64, wn = (w >> 1) * 64;

    floatx4 acc[4][4] = {};

    for (int kt = 0; kt < 256; kt += 64) {
        __syncthreads();
#pragma unroll
        for (int c4 = 0; c4 < 4; ++c4) {
            const int c = w * 4 + c4;
            const int r = c * 8 + (lane >> 3);
            const int gseg = (lane & 7) ^ (r & 7);
            const char* ga = (const char*)(A + (size_t)(m0 + r) * 256 + kt) + gseg * 16;
            const char* gb = (const char*)(Wt + (size_t)(n0 + r) * 256 + kt) + gseg * 16;
            __builtin_amdgcn_global_load_lds((const __attribute__((address_space(1))) void*)ga,
                                             (__attribute__((address_space(3))) void*)((char*)As + c * 1024),
                                             16, 0, 0);
            __builtin_amdgcn_global_load_lds((const __attribute__((address_space(1))) void*)gb,
                                             (__attribute__((address_space(3))) void*)((char*)Bs + c * 1024),
                                             16, 0, 0);
        }
        __syncthreads();

        bf16x8 af[2][4], bg[2][4];
#pragma unroll
        for (int kk = 0; kk < 2; ++kk) {
            const int s = kk * 4 + (lane >> 4);
            const int phys = s ^ (lane & 7);
#pragma unroll
            for (int i = 0; i < 4; ++i) {
                af[kk][i] = *(const bf16x8*)((const char*)As + (wm + i * 16 + (lane & 15)) * 128 + phys * 16);
                bg[kk][i] = *(const bf16x8*)((const char*)Bs + (wn + i * 16 + (lane & 15)) * 128 + phys * 16);
            }
        }
#pragma unroll
        for (int kk = 0; kk < 2; ++kk)
#pragma unroll
            for (int mi = 0; mi < 4; ++mi)
#pragma unroll
                for (int ni = 0; ni < 4; ++ni)
                    acc[mi][ni] = __builtin_amdgcn_mfma_f32_16x16x32_bf16(af[kk][mi], bg[kk][ni], acc[mi][ni], 0, 0, 0);
    }

#pragma unroll
    for (int ni = 0; ni < 4; ++ni) {
        const int col = n0 + wn + ni * 16 + (lane & 15);  // 0..767
        const int seg = col >> 8;
        const int head = (col >> 5) & 7;
        const int dim = (col & 31) + ((seg == 2) ? 32 : 0);
        const float bv = bias[col];
#pragma unroll
        for (int mi = 0; mi < 4; ++mi) {
            const int row0 = m0 + wm + mi * 16 + (lane >> 4) * 4;
#pragma unroll
            for (int r = 0; r < 4; ++r) {
                const int row = row0 + r;
                const ushort val = f2bf(acc[mi][ni][r] + bv);
                if (seg == 0)
                    qh[(size_t)head * HSZ + (size_t)row * 32 + dim] = val;
                else
                    kvh[(size_t)head * HSZ2 + (size_t)row * 64 + dim] = val;
            }
        }
    }
}

// ---------------- O-proj GEMM, 64x64 tile ----------------
__global__ __launch_bounds__(256) void gemm_mfma64(const ushort* __restrict__ A,
                                                   const ushort* __restrict__ Wt,
                                                   const float* __restrict__ bias,
                                                   float* __restrict__ outv, int N) {
    __shared__ __align__(16) ushort As[64 * 32];
    __shared__ __align__(16) ushort Bs[64 * 32];
    const int tid = threadIdx.x;
    const int w = tid >> 6, lane = tid & 63;
    const int m0 = blockIdx.y * 64, n0 = blockIdx.x * 64;
    const int row = tid >> 2;
    const int col16 = (tid & 3) * 16;

    floatx4 acc[4] = {};

    for (int kt = 0; kt < 256; kt += 32) {
        __syncthreads();
        {
            const char* ga = (const char*)(A + (size_t)(m0 + row) * 256 + kt) + col16;
            const char* gb = (const char*)(Wt + (size_t)(n0 + row) * 256 + kt) + col16;
            __builtin_amdgcn_global_load_lds((const __attribute__((address_space(1))) void*)ga,
                                             (__attribute__((address_space(3))) void*)((char*)As + w * 1024),
                                             16, 0, 0);
            __builtin_amdgcn_global_load_lds((const __attribute__((address_space(1))) void*)gb,
                                             (__attribute__((address_space(3))) void*)((char*)Bs + w * 1024),
                                             16, 0, 0);
        }
        __syncthreads();

        bf16x8 af = *(const bf16x8*)&As[(w * 16 + (lane & 15)) * 32 + (lane >> 4) * 8];
        bf16x8 bg[4];
#pragma unroll
        for (int ni = 0; ni < 4; ++ni)
            bg[ni] = *(const bf16x8*)&Bs[(ni * 16 + (lane & 15)) * 32 + (lane >> 4) * 8];
#pragma unroll
        for (int ni = 0; ni < 4; ++ni)
            acc[ni] = __builtin_amdgcn_mfma_f32_16x16x32_bf16(af, bg[ni], acc[ni], 0, 0, 0);
    }

#pragma unroll
    for (int ni = 0; ni < 4; ++ni) {
        const int col = n0 + ni * 16 + (lane & 15);
        const float bv = bias[col];
        const int row0 = m0 + w * 16 + (lane >> 4) * 4;
#pragma unroll
        for (int r = 0; r < 4; ++r)
            outv[(size_t)(row0 + r) * N + col] = acc[ni][r] + bv;
    }
}

// ---------------- attention: time-phased heads, interleaved K|V rows ----------------
// Launched as 4 dispatches of 2 heads each (hbase = 0,2,4,6): identical total
// work and same head-phased L2 locality, but each dispatch is ~12 us so any
// hidden kernel above that duration becomes visible in the profile's top-5.
//
// LDS-free. Lane mapping: s = point (lane>>4), g = neighbor group (lane>>2 & 3),
// q4 = row quarter (lane&3). 4 points/wave, 8 neighbors/lane. Each neighbor's
// K and V live in ONE 128-B line (kvh row): the V load L1-hits the K load's line.
// All 16 scattered loads are issued before any compute — one latency exposure.
__global__ __launch_bounds__(256) void attn_kernel(
    const ushort* __restrict__ qh, const ushort* __restrict__ kvh,
    const int* __restrict__ idx, const ushort* __restrict__ bias_hg, ushort* __restrict__ out,
    int hbase) {
    const int tid = threadIdx.x, wid = tid >> 6, lane = tid & 63;
    const int h = hbase + (blockIdx.x >> 10);  // head phase (slow-varying)
    const int pg = blockIdx.x & 1023;
    const int pbase = pg * 16 + wid * 4;

    const char* kv_h = (const char*)(kvh + (size_t)h * HSZ2);

    const int s = lane >> 4;
    const int g = (lane >> 2) & 3, q4 = lane & 3;
    const int p = pbase + s;
    const int b = p >> 13;

    // ---- load phase: everything this lane needs, issued up front ----
    const int4 n0 = *(const int4*)(idx + (size_t)p * 32 + g * 8);
    const int4 n1 = *(const int4*)(idx + (size_t)p * 32 + g * 8 + 4);
    const uint4 qp = *(const uint4*)(qh + (size_t)h * HSZ + p * 32 + q4 * 8);
    const uint4 bs = *(const uint4*)(bias_hg + (size_t)h * HSZ + p * 32 + g * 8);

    const uint32 roff = (uint32)(b * NPTS);
    uint32 addr[8];
    addr[0] = ((uint32)n0.x + roff) * 128u + q4 * 16;
    addr[1] = ((uint32)n0.y + roff) * 128u + q4 * 16;
    addr[2] = ((uint32)n0.z + roff) * 128u + q4 * 16;
    addr[3] = ((uint32)n0.w + roff) * 128u + q4 * 16;
    addr[4] = ((uint32)n1.x + roff) * 128u + q4 * 16;
    addr[5] = ((uint32)n1.y + roff) * 128u + q4 * 16;
    addr[6] = ((uint32)n1.z + roff) * 128u + q4 * 16;
    addr[7] = ((uint32)n1.w + roff) * 128u + q4 * 16;

    uint4 kreg[8], vreg[8];
#pragma unroll
    for (int i = 0; i < 8; ++i) kreg[i] = *(const uint4*)(kv_h + addr[i]);
#pragma unroll
    for (int i = 0; i < 8; ++i) vreg[i] = *(const uint4*)(kv_h + addr[i] + 64);

    // unpack q (this lane's 8 dims of the 32-dim row)
    const float4 qa = {bflo(qp.x), bfhi(qp.x), bflo(qp.y), bfhi(qp.y)};
    const float4 qb = {bflo(qp.z), bfhi(qp.z), bflo(qp.w), bfhi(qp.w)};

    // ---- score phase: 4 q4-lanes cooperate on each K row ----
    float e_r[8];
    float esum = 0.f;
#pragma unroll
    for (int i = 0; i < 8; ++i) {
        const uint4 kv = kreg[i];
        float d = bflo(kv.x) * qa.x + bfhi(kv.x) * qa.y
                + bflo(kv.y) * qa.z + bfhi(kv.y) * qa.w
                + bflo(kv.z) * qb.x + bfhi(kv.z) * qb.y
                + bflo(kv.w) * qb.z + bfhi(kv.w) * qb.w;
        // complete the 32-dim dot across the 4 q4 lanes
        d += __shfl_xor(d, 1, 64);
        d += __shfl_xor(d, 2, 64);
        const uint32 bw = (i < 2) ? bs.x : (i < 4) ? bs.y : (i < 6) ? bs.z : bs.w;
        const float bb = (i & 1) ? bfhi(bw) : bflo(bw);
        const float e = __expf(d * 0.17677669529663687f + bb);
        e_r[i] = e;
        esum += e;
    }
    // per-point softmax denominator: reduce over g (bits 2..3); q4 copies identical
    float ssum = esum;
    ssum += __shfl_xor(ssum, 4, 64);
    ssum += __shfl_xor(ssum, 8, 64);
    const float rinv = __builtin_amdgcn_rcpf(ssum);

    // ---- PV phase: same lane mapping; V already in registers ----
    float a0 = 0.f, a1 = 0.f, a2 = 0.f, a3 = 0.f, a4 = 0.f, a5 = 0.f, a6 = 0.f, a7 = 0.f;
#pragma unroll
    for (int i = 0; i < 8; ++i) {
        const float wgt = e_r[i];
        const uint4 v = vreg[i];
        a0 += wgt * bflo(v.x); a1 += wgt * bfhi(v.x);
        a2 += wgt * bflo(v.y); a3 += wgt * bfhi(v.y);
        a4 += wgt * bflo(v.z); a5 += wgt * bfhi(v.z);
        a6 += wgt * bflo(v.w); a7 += wgt * bfhi(v.w);
    }
    // dim-splitting butterfly over g bits (4, 8): 8 dims -> 2 dims/lane
    const bool hi4 = (lane & 4) != 0;
    {
        float t0 = hi4 ? a0 : a4, t1 = hi4 ? a1 : a5, t2 = hi4 ? a2 : a6, t3 = hi4 ? a3 : a7;
        float k0 = hi4 ? a4 : a0, k1 = hi4 ? a5 : a1, k2 = hi4 ? a6 : a2, k3 = hi4 ? a7 : a3;
        a0 = k0 + __shfl_xor(t0, 4, 64);
        a1 = k1 + __shfl_xor(t1, 4, 64);
        a2 = k2 + __shfl_xor(t2, 4, 64);
        a3 = k3 + __shfl_xor(t3, 4, 64);
    }
    const bool hi8 = (lane & 8) != 0;
    {
        float t0 = hi8 ? a0 : a2, t1 = hi8 ? a1 : a3;
        float k0 = hi8 ? a2 : a0, k1 = hi8 ? a3 : a1;
        a0 = k0 + __shfl_xor(t0, 8, 64);
        a1 = k1 + __shfl_xor(t1, 8, 64);
    }
    // lane holds dims D, D+1 with D = q4*8 + (hi4?4:0) + (hi8?2:0); packed store,
    // all 64 lanes active: 16 lanes x 4 B = 64 B contiguous per point.
    const int D = q4 * 8 + (hi4 ? 4 : 0) + (hi8 ? 2 : 0);
    const uint32 u = (uint32)f2bf(a0 * rinv) | ((uint32)f2bf(a1 * rinv) << 16);
    *(uint32*)(out + (size_t)p * 256 + h * 32 + D) = u;
}

// ---------------- launch ----------------
extern "C" void kernel_launch(void* const* d_in, const int* in_sizes, int n_in,
                              void* d_out, int out_size, void* d_ws, size_t ws_size,
                              hipStream_t stream) {
    const float* x   = (const float*)d_in[0];
    const float* xyz = (const float*)d_in[1];
    const int*   idx = (const int*)d_in[2];
    const float* Wq = (const float*)d_in[3];
    const float* bq = (const float*)d_in[4];
    const float* Wk = (const float*)d_in[5];
    const float* bk = (const float*)d_in[6];
    const float* Wv = (const float*)d_in[7];
    const float* bv = (const float*)d_in[8];
    const float* Wo = (const float*)d_in[9];
    const float* bo = (const float*)d_in[10];
    const float* W1 = (const float*)d_in[11];
    const float* b1 = (const float*)d_in[12];
    const float* W2 = (const float*)d_in[13];
    const float* b2 = (const float*)d_in[14];

    char* wsb = (char*)d_ws;
    ushort* x_bf    = (ushort*)wsb;                   // 8 MB (aliased by aout_bf)
    ushort* aout_bf = x_bf;                           // x consumed by gemm before attn writes
    ushort* qh      = (ushort*)(wsb + 8388608);       // 8 MB [8][16384][32]
    ushort* kvh     = (ushort*)(wsb + 16777216);      // 16 MB [8][16384][64] (K|V interleaved)
    ushort* bias_hg = (ushort*)(wsb + 33554432);      // 8 MB [8][16384][32]
    ushort* Wqkvt   = (ushort*)(wsb + 41943040);      // 384 KB
    ushort* Wot     = (ushort*)(wsb + 42336256);      // 128 KB
    float*  biasqkv = (float*)(wsb + 42467328);       // 3 KB

    prep_kernel<<<7168, 256, 0, stream>>>(x, xyz, idx, Wq, Wk, Wv, Wo, bq, bk, bv,
                                          W1, b1, W2, b2, x_bf, Wqkvt, Wot, biasqkv, bias_hg);

    gemm_qkv<<<dim3(6, 128), 256, 0, stream>>>(x_bf, Wqkvt, biasqkv, qh, kvh);

    attn_kernel<<<2048, 256, 0, stream>>>(qh, kvh, idx, bias_hg, aout_bf, 0);
    attn_kernel<<<2048, 256, 0, stream>>>(qh, kvh, idx, bias_hg, aout_bf, 2);
    attn_kernel<<<2048, 256, 0, stream>>>(qh, kvh, idx, bias_hg, aout_bf, 4);
    attn_kernel<<<2048, 256, 0, stream>>>(qh, kvh, idx, bias_hg, aout_bf, 6);

    gemm_mfma64<<<dim3(4, 256), 256, 0, stream>>>(aout_bf, Wot, bo, (float*)d_out, 256);
}

// Round 7
// 170.901 us; speedup vs baseline: 1.1202x; 1.0782x over previous
//
#include <hip/hip_runtime.h>
#include <hip/hip_bf16.h>

typedef unsigned int uint32;
typedef unsigned short ushort;
typedef __attribute__((ext_vector_type(4))) float floatx4;
typedef __attribute__((ext_vector_type(8))) __bf16 bf16x8;

#define NPTS 8192
#define HSZ 524288   // 16384*32 elements per head slice (q, bias)
#define HSZ2 1048576 // 16384*64 elements per head slice (interleaved K|V)

// ---------------- bf16 helpers (RNE) ----------------
__device__ __forceinline__ ushort f2bf(float f) {
    uint32 u = __float_as_uint(f);
    uint32 r = (u + 0x7fffu + ((u >> 16) & 1u)) >> 16;
    return (ushort)r;
}
__device__ __forceinline__ float bf1(ushort u) { return __uint_as_float((uint32)u << 16); }
__device__ __forceinline__ float bflo(uint32 u) { return __uint_as_float(u << 16); }
__device__ __forceinline__ float bfhi(uint32 u) { return __uint_as_float(u & 0xffff0000u); }

// ---------------- prep: cast x -> bf16 | pack weights | bias-MLP (head-major) ----------------
__global__ __launch_bounds__(256) void prep_kernel(
    const float* __restrict__ x, const float* __restrict__ xyz, const int* __restrict__ idx,
    const float* __restrict__ Wq, const float* __restrict__ Wk,
    const float* __restrict__ Wv, const float* __restrict__ Wo,
    const float* __restrict__ bq, const float* __restrict__ bk, const float* __restrict__ bv,
    const float* __restrict__ W1, const float* __restrict__ b1,
    const float* __restrict__ W2, const float* __restrict__ b2,
    ushort* __restrict__ xb, ushort* __restrict__ Wqkvt, ushort* __restrict__ Wot,
    float* __restrict__ biasqkv, ushort* __restrict__ bias_hg) {
    const int bi = blockIdx.x;
    const int tid = threadIdx.x;
    if (bi < 4096) {
        int i = (bi * 256 + tid) * 4;
        float4 v = *(const float4*)(x + i);
        ushort4 o;
        o.x = f2bf(v.x); o.y = f2bf(v.y); o.z = f2bf(v.z); o.w = f2bf(v.w);
        *(ushort4*)(xb + i) = o;
    } else if (bi < 5120) {
        int f = (bi - 4096) * 256 + tid;  // 0 .. 262143
        if (f < 768 * 256) {
            int n = f >> 8, k = f & 255;
            int seg = n >> 8, nc = n & 255;
            const float* W = (seg == 0) ? Wq : (seg == 1) ? Wk : Wv;
            Wqkvt[f] = f2bf(W[k * 256 + nc]);
        } else {
            int g = f - 768 * 256;
            int n = g >> 8, k = g & 255;
            Wot[g] = f2bf(Wo[k * 256 + n]);
        }
        if (f < 768) biasqkv[f] = (f < 256) ? bq[f] : (f < 512) ? bk[f - 256] : bv[f - 512];
    } else {
        // bias MLP: 8 points per block, 2 per wave; head-major output [h][p][j]
        __shared__ float W1s[96], b1s[32], W2s[256], b2s[8];
        if (tid < 96) W1s[tid] = W1[tid];
        if (tid < 32) b1s[tid] = b1[tid];
        W2s[tid] = W2[tid];
        if (tid < 8) b2s[tid] = b2[tid];
        __syncthreads();
        const int wid = tid >> 6, lane = tid & 63;
        const int s = lane >> 5, j = lane & 31;
        const int p = (bi - 5120) * 8 + wid * 2 + s;
        const int b = p >> 13, n = p & 8191;
        const int nj = idx[(size_t)p * 32 + j];
        const size_t pb = ((size_t)b * NPTS + n) * 3;
        const size_t nb = ((size_t)b * NPTS + nj) * 3;
        const float rx = xyz[pb + 0] - xyz[nb + 0];
        const float ry = xyz[pb + 1] - xyz[nb + 1];
        const float rz = xyz[pb + 2] - xyz[nb + 2];
        float acc[8];
#pragma unroll
        for (int h = 0; h < 8; ++h) acc[h] = b2s[h];
#pragma unroll
        for (int u = 0; u < 32; ++u) {
            float hv = rx * W1s[u] + ry * W1s[32 + u] + rz * W1s[64 + u] + b1s[u];
            hv = fmaxf(hv, 0.f);
#pragma unroll
            for (int h = 0; h < 8; ++h) acc[h] += hv * W2s[u * 8 + h];
        }
#pragma unroll
        for (int h = 0; h < 8; ++h) bias_hg[(size_t)h * HSZ + p * 32 + j] = f2bf(acc[h]);
    }
}

// ---------------- QKV GEMM: 128x128 tile, BK=64, XOR-swizzled LDS ----------------
// out scattered head-major: qh[h][p][32]; kvh[h][p][64] with K in dims 0-31, V in 32-63
// (one 128-B cache line holds both K and V rows of a neighbor).
__global__ __launch_bounds__(256) void gemm_qkv(const ushort* __restrict__ A,
                                                const ushort* __restrict__ Wt,
                                                const float* __restrict__ bias,
                                                ushort* __restrict__ qh,
                                                ushort* __restrict__ kvh) {
    __shared__ __align__(16) ushort As[128 * 64];
    __shared__ __align__(16) ushort Bs[128 * 64];
    const int tid = threadIdx.x;
    const int w = tid >> 6, lane = tid & 63;
    const int m0 = blockIdx.y * 128, n0 = blockIdx.x * 128;
    const int wm = (w & 1) * 64, wn = (w >> 1) * 64;

    floatx4 acc[4][4] = {};

    for (int kt = 0; kt < 256; kt += 64) {
        __syncthreads();
#pragma unroll
        for (int c4 = 0; c4 < 4; ++c4) {
            const int c = w * 4 + c4;
            const int r = c * 8 + (lane >> 3);
            const int gseg = (lane & 7) ^ (r & 7);
            const char* ga = (const char*)(A + (size_t)(m0 + r) * 256 + kt) + gseg * 16;
            const char* gb = (const char*)(Wt + (size_t)(n0 + r) * 256 + kt) + gseg * 16;
            __builtin_amdgcn_global_load_lds((const __attribute__((address_space(1))) void*)ga,
                                             (__attribute__((address_space(3))) void*)((char*)As + c * 1024),
                                             16, 0, 0);
            __builtin_amdgcn_global_load_lds((const __attribute__((address_space(1))) void*)gb,
                                             (__attribute__((address_space(3))) void*)((char*)Bs + c * 1024),
                                             16, 0, 0);
        }
        __syncthreads();

        bf16x8 af[2][4], bg[2][4];
#pragma unroll
        for (int kk = 0; kk < 2; ++kk) {
            const int s = kk * 4 + (lane >> 4);
            const int phys = s ^ (lane & 7);
#pragma unroll
            for (int i = 0; i < 4; ++i) {
                af[kk][i] = *(const bf16x8*)((const char*)As + (wm + i * 16 + (lane & 15)) * 128 + phys * 16);
                bg[kk][i] = *(const bf16x8*)((const char*)Bs + (wn + i * 16 + (lane & 15)) * 128 + phys * 16);
            }
        }
#pragma unroll
        for (int kk = 0; kk < 2; ++kk)
#pragma unroll
            for (int mi = 0; mi < 4; ++mi)
#pragma unroll
                for (int ni = 0; ni < 4; ++ni)
                    acc[mi][ni] = __builtin_amdgcn_mfma_f32_16x16x32_bf16(af[kk][mi], bg[kk][ni], acc[mi][ni], 0, 0, 0);
    }

#pragma unroll
    for (int ni = 0; ni < 4; ++ni) {
        const int col = n0 + wn + ni * 16 + (lane & 15);  // 0..767
        const int seg = col >> 8;
        const int head = (col >> 5) & 7;
        const int dim = (col & 31) + ((seg == 2) ? 32 : 0);
        const float bv = bias[col];
#pragma unroll
        for (int mi = 0; mi < 4; ++mi) {
            const int row0 = m0 + wm + mi * 16 + (lane >> 4) * 4;
#pragma unroll
            for (int r = 0; r < 4; ++r) {
                const int row = row0 + r;
                const ushort val = f2bf(acc[mi][ni][r] + bv);
                if (seg == 0)
                    qh[(size_t)head * HSZ + (size_t)row * 32 + dim] = val;
                else
                    kvh[(size_t)head * HSZ2 + (size_t)row * 64 + dim] = val;
            }
        }
    }
}

// ---------------- O-proj GEMM: same 128x128/BK=64 structure, dense fp32 epilogue ----------------
// Replaces the old 64x64/BK=32 version: that one had 8 K-iterations x 2 barriers
// with only 4 MFMAs/wave between barriers (barrier-latency-bound). This body is
// the proven gemm_qkv pipeline; grid (2,128) = 256 blocks = exactly 1/CU.
__global__ __launch_bounds__(256) void gemm_oproj(const ushort* __restrict__ A,
                                                  const ushort* __restrict__ Wt,
                                                  const float* __restrict__ bias,
                                                  float* __restrict__ outv) {
    __shared__ __align__(16) ushort As[128 * 64];
    __shared__ __align__(16) ushort Bs[128 * 64];
    const int tid = threadIdx.x;
    const int w = tid >> 6, lane = tid & 63;
    const int m0 = blockIdx.y * 128, n0 = blockIdx.x * 128;
    const int wm = (w & 1) * 64, wn = (w >> 1) * 64;

    floatx4 acc[4][4] = {};

    for (int kt = 0; kt < 256; kt += 64) {
        __syncthreads();
#pragma unroll
        for (int c4 = 0; c4 < 4; ++c4) {
            const int c = w * 4 + c4;
            const int r = c * 8 + (lane >> 3);
            const int gseg = (lane & 7) ^ (r & 7);
            const char* ga = (const char*)(A + (size_t)(m0 + r) * 256 + kt) + gseg * 16;
            const char* gb = (const char*)(Wt + (size_t)(n0 + r) * 256 + kt) + gseg * 16;
            __builtin_amdgcn_global_load_lds((const __attribute__((address_space(1))) void*)ga,
                                             (__attribute__((address_space(3))) void*)((char*)As + c * 1024),
                                             16, 0, 0);
            __builtin_amdgcn_global_load_lds((const __attribute__((address_space(1))) void*)gb,
                                             (__attribute__((address_space(3))) void*)((char*)Bs + c * 1024),
                                             16, 0, 0);
        }
        __syncthreads();

        bf16x8 af[2][4], bg[2][4];
#pragma unroll
        for (int kk = 0; kk < 2; ++kk) {
            const int s = kk * 4 + (lane >> 4);
            const int phys = s ^ (lane & 7);
#pragma unroll
            for (int i = 0; i < 4; ++i) {
                af[kk][i] = *(const bf16x8*)((const char*)As + (wm + i * 16 + (lane & 15)) * 128 + phys * 16);
                bg[kk][i] = *(const bf16x8*)((const char*)Bs + (wn + i * 16 + (lane & 15)) * 128 + phys * 16);
            }
        }
#pragma unroll
        for (int kk = 0; kk < 2; ++kk)
#pragma unroll
            for (int mi = 0; mi < 4; ++mi)
#pragma unroll
                for (int ni = 0; ni < 4; ++ni)
                    acc[mi][ni] = __builtin_amdgcn_mfma_f32_16x16x32_bf16(af[kk][mi], bg[kk][ni], acc[mi][ni], 0, 0, 0);
    }

#pragma unroll
    for (int ni = 0; ni < 4; ++ni) {
        const int col = n0 + wn + ni * 16 + (lane & 15);  // 0..255
        const float bv = bias[col];
#pragma unroll
        for (int mi = 0; mi < 4; ++mi) {
            const int row0 = m0 + wm + mi * 16 + (lane >> 4) * 4;
#pragma unroll
            for (int r = 0; r < 4; ++r)
                outv[(size_t)(row0 + r) * 256 + col] = acc[mi][ni][r] + bv;
        }
    }
}

// ---------------- attention: time-phased heads, interleaved K|V rows ----------------
// blockIdx = head*1024 + pg: resident blocks cluster on 1-2 heads so each XCD's
// L2 holds the current head's K|V slice (2 MB). Single dispatch: round-6 measured
// dispatch overhead at ~3.4 us each, so splitting is a net loss.
//
// LDS-free. Lane mapping: s = point (lane>>4), g = neighbor group (lane>>2 & 3),
// q4 = row quarter (lane&3). 4 points/wave, 8 neighbors/lane. Each neighbor's
// K and V live in ONE 128-B line (kvh row): the V load L1-hits the K load's line.
// All 16 scattered loads are issued before any compute — one latency exposure.
__global__ __launch_bounds__(256) void attn_kernel(
    const ushort* __restrict__ qh, const ushort* __restrict__ kvh,
    const int* __restrict__ idx, const ushort* __restrict__ bias_hg, ushort* __restrict__ out) {
    const int tid = threadIdx.x, wid = tid >> 6, lane = tid & 63;
    const int h = blockIdx.x >> 10;       // head phase (slow-varying)
    const int pg = blockIdx.x & 1023;
    const int pbase = pg * 16 + wid * 4;

    const char* kv_h = (const char*)(kvh + (size_t)h * HSZ2);

    const int s = lane >> 4;
    const int g = (lane >> 2) & 3, q4 = lane & 3;
    const int p = pbase + s;
    const int b = p >> 13;

    // ---- load phase: everything this lane needs, issued up front ----
    const int4 n0 = *(const int4*)(idx + (size_t)p * 32 + g * 8);
    const int4 n1 = *(const int4*)(idx + (size_t)p * 32 + g * 8 + 4);
    const uint4 qp = *(const uint4*)(qh + (size_t)h * HSZ + p * 32 + q4 * 8);
    const uint4 bs = *(const uint4*)(bias_hg + (size_t)h * HSZ + p * 32 + g * 8);

    const uint32 roff = (uint32)(b * NPTS);
    uint32 addr[8];
    addr[0] = ((uint32)n0.x + roff) * 128u + q4 * 16;
    addr[1] = ((uint32)n0.y + roff) * 128u + q4 * 16;
    addr[2] = ((uint32)n0.z + roff) * 128u + q4 * 16;
    addr[3] = ((uint32)n0.w + roff) * 128u + q4 * 16;
    addr[4] = ((uint32)n1.x + roff) * 128u + q4 * 16;
    addr[5] = ((uint32)n1.y + roff) * 128u + q4 * 16;
    addr[6] = ((uint32)n1.z + roff) * 128u + q4 * 16;
    addr[7] = ((uint32)n1.w + roff) * 128u + q4 * 16;

    uint4 kreg[8], vreg[8];
#pragma unroll
    for (int i = 0; i < 8; ++i) kreg[i] = *(const uint4*)(kv_h + addr[i]);
#pragma unroll
    for (int i = 0; i < 8; ++i) vreg[i] = *(const uint4*)(kv_h + addr[i] + 64);

    // unpack q (this lane's 8 dims of the 32-dim row)
    const float4 qa = {bflo(qp.x), bfhi(qp.x), bflo(qp.y), bfhi(qp.y)};
    const float4 qb = {bflo(qp.z), bfhi(qp.z), bflo(qp.w), bfhi(qp.w)};

    // ---- score phase: 4 q4-lanes cooperate on each K row ----
    float e_r[8];
    float esum = 0.f;
#pragma unroll
    for (int i = 0; i < 8; ++i) {
        const uint4 kv = kreg[i];
        float d = bflo(kv.x) * qa.x + bfhi(kv.x) * qa.y
                + bflo(kv.y) * qa.z + bfhi(kv.y) * qa.w
                + bflo(kv.z) * qb.x + bfhi(kv.z) * qb.y
                + bflo(kv.w) * qb.z + bfhi(kv.w) * qb.w;
        // complete the 32-dim dot across the 4 q4 lanes
        d += __shfl_xor(d, 1, 64);
        d += __shfl_xor(d, 2, 64);
        const uint32 bw = (i < 2) ? bs.x : (i < 4) ? bs.y : (i < 6) ? bs.z : bs.w;
        const float bb = (i & 1) ? bfhi(bw) : bflo(bw);
        const float e = __expf(d * 0.17677669529663687f + bb);
        e_r[i] = e;
        esum += e;
    }
    // per-point softmax denominator: reduce over g (bits 2..3); q4 copies identical
    float ssum = esum;
    ssum += __shfl_xor(ssum, 4, 64);
    ssum += __shfl_xor(ssum, 8, 64);
    const float rinv = __builtin_amdgcn_rcpf(ssum);

    // ---- PV phase: same lane mapping; V already in registers ----
    float a0 = 0.f, a1 = 0.f, a2 = 0.f, a3 = 0.f, a4 = 0.f, a5 = 0.f, a6 = 0.f, a7 = 0.f;
#pragma unroll
    for (int i = 0; i < 8; ++i) {
        const float wgt = e_r[i];
        const uint4 v = vreg[i];
        a0 += wgt * bflo(v.x); a1 += wgt * bfhi(v.x);
        a2 += wgt * bflo(v.y); a3 += wgt * bfhi(v.y);
        a4 += wgt * bflo(v.z); a5 += wgt * bfhi(v.z);
        a6 += wgt * bflo(v.w); a7 += wgt * bfhi(v.w);
    }
    // dim-splitting butterfly over g bits (4, 8): 8 dims -> 2 dims/lane
    const bool hi4 = (lane & 4) != 0;
    {
        float t0 = hi4 ? a0 : a4, t1 = hi4 ? a1 : a5, t2 = hi4 ? a2 : a6, t3 = hi4 ? a3 : a7;
        float k0 = hi4 ? a4 : a0, k1 = hi4 ? a5 : a1, k2 = hi4 ? a6 : a2, k3 = hi4 ? a7 : a3;
        a0 = k0 + __shfl_xor(t0, 4, 64);
        a1 = k1 + __shfl_xor(t1, 4, 64);
        a2 = k2 + __shfl_xor(t2, 4, 64);
        a3 = k3 + __shfl_xor(t3, 4, 64);
    }
    const bool hi8 = (lane & 8) != 0;
    {
        float t0 = hi8 ? a0 : a2, t1 = hi8 ? a1 : a3;
        float k0 = hi8 ? a2 : a0, k1 = hi8 ? a3 : a1;
        a0 = k0 + __shfl_xor(t0, 8, 64);
        a1 = k1 + __shfl_xor(t1, 8, 64);
    }
    // lane holds dims D, D+1 with D = q4*8 + (hi4?4:0) + (hi8?2:0); packed store,
    // all 64 lanes active: 16 lanes x 4 B = 64 B contiguous per point.
    const int D = q4 * 8 + (hi4 ? 4 : 0) + (hi8 ? 2 : 0);
    const uint32 u = (uint32)f2bf(a0 * rinv) | ((uint32)f2bf(a1 * rinv) << 16);
    *(uint32*)(out + (size_t)p * 256 + h * 32 + D) = u;
}

// ---------------- launch ----------------
extern "C" void kernel_launch(void* const* d_in, const int* in_sizes, int n_in,
                              void* d_out, int out_size, void* d_ws, size_t ws_size,
                              hipStream_t stream) {
    const float* x   = (const float*)d_in[0];
    const float* xyz = (const float*)d_in[1];
    const int*   idx = (const int*)d_in[2];
    const float* Wq = (const float*)d_in[3];
    const float* bq = (const float*)d_in[4];
    const float* Wk = (const float*)d_in[5];
    const float* bk = (const float*)d_in[6];
    const float* Wv = (const float*)d_in[7];
    const float* bv = (const float*)d_in[8];
    const float* Wo = (const float*)d_in[9];
    const float* bo = (const float*)d_in[10];
    const float* W1 = (const float*)d_in[11];
    const float* b1 = (const float*)d_in[12];
    const float* W2 = (const float*)d_in[13];
    const float* b2 = (const float*)d_in[14];

    char* wsb = (char*)d_ws;
    ushort* x_bf    = (ushort*)wsb;                   // 8 MB (aliased by aout_bf)
    ushort* aout_bf = x_bf;                           // x consumed by gemm before attn writes
    ushort* qh      = (ushort*)(wsb + 8388608);       // 8 MB [8][16384][32]
    ushort* kvh     = (ushort*)(wsb + 16777216);      // 16 MB [8][16384][64] (K|V interleaved)
    ushort* bias_hg = (ushort*)(wsb + 33554432);      // 8 MB [8][16384][32]
    ushort* Wqkvt   = (ushort*)(wsb + 41943040);      // 384 KB
    ushort* Wot     = (ushort*)(wsb + 42336256);      // 128 KB
    float*  biasqkv = (float*)(wsb + 42467328);       // 3 KB

    prep_kernel<<<7168, 256, 0, stream>>>(x, xyz, idx, Wq, Wk, Wv, Wo, bq, bk, bv,
                                          W1, b1, W2, b2, x_bf, Wqkvt, Wot, biasqkv, bias_hg);

    gemm_qkv<<<dim3(6, 128), 256, 0, stream>>>(x_bf, Wqkvt, biasqkv, qh, kvh);

    attn_kernel<<<8192, 256, 0, stream>>>(qh, kvh, idx, bias_hg, aout_bf);

    gemm_oproj<<<dim3(2, 128), 256, 0, stream>>>(aout_bf, Wot, bo, (float*)d_out);
}